// Round 6
// baseline (195.794 us; speedup 1.0000x reference)
//
#include <hip/hip_runtime.h>

typedef short short8 __attribute__((ext_vector_type(8)));
typedef _Float16 half8 __attribute__((ext_vector_type(8)));
typedef float floatx4 __attribute__((ext_vector_type(4)));
typedef __attribute__((address_space(1))) const void gvoid;
typedef __attribute__((address_space(3))) void svoid;

#define SCALE_POS 2.0f
#define SCALE_NEG 40.0f
#define THRESH 0.5f
#define MARGIN 0.1f
#define EPSV 1e-5f

__device__ __forceinline__ unsigned short f2bf(float f) {
    unsigned u = __float_as_uint(f);
    u += 0x7fffu + ((u >> 16) & 1u);   // round-to-nearest-even
    return (unsigned short)(u >> 16);
}
// order-preserving float<->uint map (no NaNs present)
__device__ __forceinline__ unsigned f2ord(float f) {
    unsigned u = __float_as_uint(f);
    return (u & 0x80000000u) ? ~u : (u | 0x80000000u);
}
__device__ __forceinline__ float ord2f(unsigned e) {
    unsigned v = (e & 0x80000000u) ? (e & 0x7fffffffu) : ~e;
    return __uint_as_float(v);
}

#define ORD_POS_INF 0xff800000u   // f2ord(+inf)
#define ORD_NEG_INF 0x007fffffu   // f2ord(-inf)

// relaxed agent-scope atomic helpers (coherent access, NO wbl2/inv fences)
__device__ __forceinline__ unsigned aload_u32(const unsigned* p) {
    return __hip_atomic_load(p, __ATOMIC_RELAXED, __HIP_MEMORY_SCOPE_AGENT);
}
__device__ __forceinline__ float aload_f32(const float* p) {
    return __hip_atomic_load(p, __ATOMIC_RELAXED, __HIP_MEMORY_SCOPE_AGENT);
}
__device__ __forceinline__ void ainc_u32(unsigned* p) {
    __hip_atomic_fetch_add(p, 1u, __ATOMIC_RELAXED, __HIP_MEMORY_SCOPE_AGENT);
}

// ---- kernel 1: fp32 -> bf16 cast + stat/counter init ----
__global__ void k_init(const float* __restrict__ feats,
                       unsigned short* __restrict__ fb16,
                       unsigned* __restrict__ minp, unsigned* __restrict__ maxn,
                       float* __restrict__ psum, float* __restrict__ nsum,
                       unsigned* __restrict__ cnts,
                       int total4, int B) {
    int i = blockIdx.x * blockDim.x + threadIdx.x;
    if (i < total4) {
        float4 v = ((const float4*)feats)[i];
        ushort4 o;
        o.x = f2bf(v.x); o.y = f2bf(v.y); o.z = f2bf(v.z); o.w = f2bf(v.w);
        ((ushort4*)fb16)[i] = o;
    }
    if (i < B) {
        minp[i] = ORD_POS_INF;
        maxn[i] = ORD_NEG_INF;
        psum[i] = 0.f;
        nsum[i] = 0.f;
    }
    if (i < 64) cnts[i] = 0;   // arrive[0..31], done @32, fb done @33
}

// =====================================================================
// kernel 2 (primary): fully fused similarity-loss kernel.
// 1024 blocks = 4/CU co-resident (cooperative launch):
//   blocks 0..nb-1      : diagonal 128x128 tiles (A staged once, B=A)
//   blocks nb..1023     : off-diag 64x128 half-tiles (2 per upper-tri tile)
// Flow: GEMM -> stat atomics -> relaxed-atomic arrival sync (NO fences,
// no L2 flush) -> gated exp sums from LIVE accumulators -> psum/nsum
// atomics -> last-block scalar reduction.
// =====================================================================
__global__ void __launch_bounds__(256, 4)
k_main(const unsigned short* __restrict__ fb16,
       const int* __restrict__ labels,
       unsigned* __restrict__ minp_ord, unsigned* __restrict__ maxn_ord,
       float* __restrict__ psum, float* __restrict__ nsum,
       unsigned* __restrict__ arrive, unsigned* __restrict__ done_cnt,
       float* __restrict__ out,
       int D, int nb, int B) {
    __shared__ __align__(16) unsigned short As[128 * 32];  // 8 KB
    __shared__ __align__(16) unsigned short Bs[128 * 32];  // 8 KB
    __shared__ int labR[128], labC[128];
    __shared__ float mpR[128], mnR[128], mpC[128], mnC[128];
    __shared__ float red[4];
    __shared__ unsigned lastflag;

    const int tid = threadIdx.x;
    const int lane = tid & 63;
    const int wave = tid >> 6;
    const int q = lane >> 4;
    const int cIn = lane & 15;
    const int srow = lane >> 2;
    const int scol = (lane & 3) * 8;
    const int KT = D >> 5;
    const unsigned target = 2u * (unsigned)nb - 1u;

    if (blockIdx.x < (unsigned)nb) {
        // ================= DIAGONAL 128x128 tile =================
        const int rb = blockIdx.x;
        const int rowBase = rb * 128;
        const int wr = wave >> 1, wc = wave & 1;

        if (tid < 128) labR[tid] = labels[rowBase + tid];

        // staging: 8 chunks of 1KB into As only (B operand == A tile)
        const int c0 = wave * 2, c1 = c0 + 1;
        const unsigned short* gA0 = fb16 + (size_t)(rowBase + c0 * 16 + srow) * D + scol;
        const unsigned short* gA1 = fb16 + (size_t)(rowBase + c1 * 16 + srow) * D + scol;
        unsigned short* lA0 = As + c0 * 512 + lane * 8;
        unsigned short* lA1 = As + c1 * 512 + lane * 8;

        int aOff[4], bOff[4];
#pragma unroll
        for (int i = 0; i < 4; ++i) {
            aOff[i] = (wr * 64 + i * 16 + cIn) * 32 + q * 8;
            bOff[i] = (wc * 64 + i * 16 + cIn) * 32 + q * 8;
        }

        floatx4 acc[4][4] = {};
        for (int kt = 0; kt < KT; ++kt) {
            const int kOff = kt * 32;
            __syncthreads();
            __builtin_amdgcn_global_load_lds((gvoid*)(gA0 + kOff), (svoid*)lA0, 16, 0, 0);
            __builtin_amdgcn_global_load_lds((gvoid*)(gA1 + kOff), (svoid*)lA1, 16, 0, 0);
            __syncthreads();
            short8 a[4], b[4];
#pragma unroll
            for (int i = 0; i < 4; ++i) a[i] = *(const short8*)(As + aOff[i]);
#pragma unroll
            for (int i = 0; i < 4; ++i) b[i] = *(const short8*)(As + bOff[i]);
#pragma unroll
            for (int i = 0; i < 4; ++i)
#pragma unroll
                for (int j = 0; j < 4; ++j)
                    acc[i][j] = __builtin_amdgcn_mfma_f32_16x16x32_bf16(a[i], b[j], acc[i][j], 0, 0, 0);
        }

        int cLabv[4];
#pragma unroll
        for (int ni = 0; ni < 4; ++ni) cLabv[ni] = labR[wc * 64 + ni * 16 + cIn];

        // row stats only (rows==cols for diagonal tile)
#pragma unroll
        for (int mi = 0; mi < 4; ++mi)
#pragma unroll
            for (int rr = 0; rr < 4; ++rr) {
                const int rLoc = wr * 64 + mi * 16 + q * 4 + rr;
                const int rLab = labR[rLoc];
                float vmin = 1e30f, vmax = -1e30f;
#pragma unroll
                for (int ni = 0; ni < 4; ++ni) {
                    float s = acc[mi][ni][rr];
                    if (rLab == cLabv[ni]) {
                        if (s < 1.0f - EPSV) vmin = fminf(vmin, s);
                    } else {
                        vmax = fmaxf(vmax, s);
                    }
                }
#pragma unroll
                for (int off = 8; off; off >>= 1) {
                    vmin = fminf(vmin, __shfl_xor(vmin, off, 16));
                    vmax = fmaxf(vmax, __shfl_xor(vmax, off, 16));
                }
                if (cIn == 0) {
                    if (vmin < 1e30f) atomicMin(&minp_ord[rowBase + rLoc], f2ord(vmin));
                    if (vmax > -1e30f) atomicMax(&maxn_ord[rowBase + rLoc], f2ord(vmax));
                }
            }

        // arrival sync (relaxed agent atomics only — no cache flushes)
        __syncthreads();               // drains vmcnt: stats atomics complete
        if (tid == 0) {
            ainc_u32(&arrive[rb]);
            while (aload_u32(&arrive[rb]) < target) __builtin_amdgcn_s_sleep(2);
        }
        __syncthreads();

        // load final gates
        if (tid < 128) {
            mpR[tid] = ord2f(aload_u32(&minp_ord[rowBase + tid])) - MARGIN;  // neg kept if s > this
            mnR[tid] = ord2f(aload_u32(&maxn_ord[rowBase + tid])) + MARGIN;  // pos kept if s < this
        }
        __syncthreads();

        // gated exp sums (row direction only)
#pragma unroll
        for (int mi = 0; mi < 4; ++mi)
#pragma unroll
            for (int rr = 0; rr < 4; ++rr) {
                const int rLoc = wr * 64 + mi * 16 + q * 4 + rr;
                const int rLab = labR[rLoc];
                const float gateN = mpR[rLoc], gateP = mnR[rLoc];
                float rp = 0.f, rn = 0.f;
#pragma unroll
                for (int ni = 0; ni < 4; ++ni) {
                    const float s = acc[mi][ni][rr];
                    if (rLab == cLabv[ni]) {
                        if (s < 1.0f - EPSV && s < gateP) rp += __expf(-SCALE_POS * (s - THRESH));
                    } else {
                        if (s > gateN) rn += __expf(SCALE_NEG * (s - THRESH));
                    }
                }
#pragma unroll
                for (int off = 8; off; off >>= 1) {
                    rp += __shfl_xor(rp, off, 16);
                    rn += __shfl_xor(rn, off, 16);
                }
                if (cIn == 0) {
                    if (rp != 0.f) atomicAdd(&psum[rowBase + rLoc], rp);
                    if (rn != 0.f) atomicAdd(&nsum[rowBase + rLoc], rn);
                }
            }
    } else {
        // ================= OFF-DIAG 64x128 half-tile =================
        const int e = blockIdx.x - nb;
        const int h = e & 1;
        int p = e >> 1;
        int rb = 0;
        while (p >= nb - 1 - rb) { p -= nb - 1 - rb; ++rb; }
        const int cb = rb + 1 + p;
        const int rowB = rb * 128 + h * 64;   // 64 rows
        const int colB = cb * 128;            // 128 cols
        const int wr = wave >> 1, wc = wave & 1;   // wave = 32-row x 64-col quadrant

        if (tid < 64)        labR[tid] = labels[rowB + tid];
        else if (tid >= 128) labC[tid - 128] = labels[colB + tid - 128];

        // staging: A 4 chunks + B 8 chunks = 12 x 1KB; wave handles 3 chunks
        const unsigned short* gC[3];
        unsigned short* lC[3];
#pragma unroll
        for (int j = 0; j < 3; ++j) {
            const int cc = wave * 3 + j;
            if (cc < 4) {
                gC[j] = fb16 + (size_t)(rowB + cc * 16 + srow) * D + scol;
                lC[j] = As + cc * 512 + lane * 8;
            } else {
                gC[j] = fb16 + (size_t)(colB + (cc - 4) * 16 + srow) * D + scol;
                lC[j] = Bs + (cc - 4) * 512 + lane * 8;
            }
        }

        int aOff[2], bOff[4];
#pragma unroll
        for (int i = 0; i < 2; ++i) aOff[i] = (wr * 32 + i * 16 + cIn) * 32 + q * 8;
#pragma unroll
        for (int i = 0; i < 4; ++i) bOff[i] = (wc * 64 + i * 16 + cIn) * 32 + q * 8;

        floatx4 acc[2][4] = {};
        for (int kt = 0; kt < KT; ++kt) {
            const int kOff = kt * 32;
            __syncthreads();
            __builtin_amdgcn_global_load_lds((gvoid*)(gC[0] + kOff), (svoid*)lC[0], 16, 0, 0);
            __builtin_amdgcn_global_load_lds((gvoid*)(gC[1] + kOff), (svoid*)lC[1], 16, 0, 0);
            __builtin_amdgcn_global_load_lds((gvoid*)(gC[2] + kOff), (svoid*)lC[2], 16, 0, 0);
            __syncthreads();
            short8 a[2], b[4];
#pragma unroll
            for (int i = 0; i < 2; ++i) a[i] = *(const short8*)(As + aOff[i]);
#pragma unroll
            for (int i = 0; i < 4; ++i) b[i] = *(const short8*)(Bs + bOff[i]);
#pragma unroll
            for (int i = 0; i < 2; ++i)
#pragma unroll
                for (int j = 0; j < 4; ++j)
                    acc[i][j] = __builtin_amdgcn_mfma_f32_16x16x32_bf16(a[i], b[j], acc[i][j], 0, 0, 0);
        }

        int cLabv[4];
#pragma unroll
        for (int ni = 0; ni < 4; ++ni) cLabv[ni] = labC[wc * 64 + ni * 16 + cIn];

        // row stats (this half's 64 rows)
#pragma unroll
        for (int mi = 0; mi < 2; ++mi)
#pragma unroll
            for (int rr = 0; rr < 4; ++rr) {
                const int rLoc = wr * 32 + mi * 16 + q * 4 + rr;
                const int rLab = labR[rLoc];
                float vmin = 1e30f, vmax = -1e30f;
#pragma unroll
                for (int ni = 0; ni < 4; ++ni) {
                    float s = acc[mi][ni][rr];
                    if (rLab == cLabv[ni]) {
                        if (s < 1.0f - EPSV) vmin = fminf(vmin, s);
                    } else {
                        vmax = fmaxf(vmax, s);
                    }
                }
#pragma unroll
                for (int off = 8; off; off >>= 1) {
                    vmin = fminf(vmin, __shfl_xor(vmin, off, 16));
                    vmax = fmaxf(vmax, __shfl_xor(vmax, off, 16));
                }
                if (cIn == 0) {
                    if (vmin < 1e30f) atomicMin(&minp_ord[rowB + rLoc], f2ord(vmin));
                    if (vmax > -1e30f) atomicMax(&maxn_ord[rowB + rLoc], f2ord(vmax));
                }
            }
        // col stats via symmetry (128 cols over this half's 64 rows)
#pragma unroll
        for (int ni = 0; ni < 4; ++ni) {
            const int cLab = cLabv[ni];
            float vmin = 1e30f, vmax = -1e30f;
#pragma unroll
            for (int mi = 0; mi < 2; ++mi)
#pragma unroll
                for (int rr = 0; rr < 4; ++rr) {
                    float s = acc[mi][ni][rr];
                    if (labR[wr * 32 + mi * 16 + q * 4 + rr] == cLab) {
                        if (s < 1.0f - EPSV) vmin = fminf(vmin, s);
                    } else {
                        vmax = fmaxf(vmax, s);
                    }
                }
            vmin = fminf(vmin, __shfl_xor(vmin, 16, 64));
            vmin = fminf(vmin, __shfl_xor(vmin, 32, 64));
            vmax = fmaxf(vmax, __shfl_xor(vmax, 16, 64));
            vmax = fmaxf(vmax, __shfl_xor(vmax, 32, 64));
            if (q == 0) {
                const int cLoc = wc * 64 + ni * 16 + cIn;
                if (vmin < 1e30f) atomicMin(&minp_ord[colB + cLoc], f2ord(vmin));
                if (vmax > -1e30f) atomicMax(&maxn_ord[colB + cLoc], f2ord(vmax));
            }
        }

        // arrival sync
        __syncthreads();
        if (tid == 0) {
            ainc_u32(&arrive[rb]);
            ainc_u32(&arrive[cb]);
            while (aload_u32(&arrive[rb]) < target) __builtin_amdgcn_s_sleep(2);
            while (aload_u32(&arrive[cb]) < target) __builtin_amdgcn_s_sleep(2);
        }
        __syncthreads();

        if (tid < 64) {
            mpR[tid] = ord2f(aload_u32(&minp_ord[rowB + tid])) - MARGIN;
            mnR[tid] = ord2f(aload_u32(&maxn_ord[rowB + tid])) + MARGIN;
        } else if (tid >= 128) {
            const int j = tid - 128;
            mpC[j] = ord2f(aload_u32(&minp_ord[colB + j])) - MARGIN;
            mnC[j] = ord2f(aload_u32(&maxn_ord[colB + j])) + MARGIN;
        }
        __syncthreads();

        float cps[4] = {}, cns[4] = {};
#pragma unroll
        for (int mi = 0; mi < 2; ++mi)
#pragma unroll
            for (int rr = 0; rr < 4; ++rr) {
                const int rLoc = wr * 32 + mi * 16 + q * 4 + rr;
                const int rLab = labR[rLoc];
                const float gateN = mpR[rLoc], gateP = mnR[rLoc];
                float rp = 0.f, rn = 0.f;
#pragma unroll
                for (int ni = 0; ni < 4; ++ni) {
                    const float s = acc[mi][ni][rr];
                    const int cLoc = wc * 64 + ni * 16 + cIn;
                    if (rLab == cLabv[ni]) {
                        if (s < 1.0f - EPSV) {
                            float ev = __expf(-SCALE_POS * (s - THRESH));
                            if (s < gateP) rp += ev;
                            if (s < mnC[cLoc]) cps[ni] += ev;
                        }
                    } else {
                        float ev = __expf(SCALE_NEG * (s - THRESH));
                        if (s > gateN) rn += ev;
                        if (s > mpC[cLoc]) cns[ni] += ev;
                    }
                }
#pragma unroll
                for (int off = 8; off; off >>= 1) {
                    rp += __shfl_xor(rp, off, 16);
                    rn += __shfl_xor(rn, off, 16);
                }
                if (cIn == 0) {
                    if (rp != 0.f) atomicAdd(&psum[rowB + rLoc], rp);
                    if (rn != 0.f) atomicAdd(&nsum[rowB + rLoc], rn);
                }
            }
#pragma unroll
        for (int ni = 0; ni < 4; ++ni) {
            cps[ni] += __shfl_xor(cps[ni], 16, 64);
            cps[ni] += __shfl_xor(cps[ni], 32, 64);
            cns[ni] += __shfl_xor(cns[ni], 16, 64);
            cns[ni] += __shfl_xor(cns[ni], 32, 64);
            if (q == 0) {
                const int cLoc = wc * 64 + ni * 16 + cIn;
                if (cps[ni] != 0.f) atomicAdd(&psum[colB + cLoc], cps[ni]);
                if (cns[ni] != 0.f) atomicAdd(&nsum[colB + cLoc], cns[ni]);
            }
        }
    }

    // ---- last-block scalar reduction ----
    __syncthreads();   // drains vmcnt: this block's psum/nsum atomics complete
    if (tid == 0) {
        unsigned prev = __hip_atomic_fetch_add(done_cnt, 1u, __ATOMIC_RELAXED,
                                               __HIP_MEMORY_SCOPE_AGENT);
        lastflag = (prev == gridDim.x - 1) ? 1u : 0u;
    }
    __syncthreads();
    if (lastflag) {
        float a = 0.f;
        for (int i = tid; i < B; i += 256) {
            float pv = aload_f32(&psum[i]);
            float nv = aload_f32(&nsum[i]);
            if (pv > 0.f && nv > 0.f)
                a += log1pf(pv) * (1.0f / SCALE_POS) + log1pf(nv) * (1.0f / SCALE_NEG);
        }
#pragma unroll
        for (int off = 32; off; off >>= 1) a += __shfl_down(a, off, 64);
        if ((tid & 63) == 0) red[tid >> 6] = a;
        __syncthreads();
        if (tid == 0) out[0] = (red[0] + red[1] + red[2] + red[3]) / (float)B;
    }
}

// =====================================================================
// FALLBACK PATH (non-cooperative, round-2 structure — proven correct)
// =====================================================================
__global__ void k_gemm_sym(const unsigned short* __restrict__ fb16,
                           const int* __restrict__ labels,
                           unsigned* __restrict__ minp_ord,
                           unsigned* __restrict__ maxn_ord,
                           _Float16* __restrict__ simh,
                           int D, int nb) {
    __shared__ __align__(16) unsigned short As[128 * 32];
    __shared__ __align__(16) unsigned short Bs[128 * 32];
    __shared__ int labR[128], labC[128];

    int t = blockIdx.x;
    int rb = 0, rem = t;
    while (rem >= nb - rb) { rem -= nb - rb; ++rb; }
    const int cb = rb + rem;

    const int tid = threadIdx.x;
    const int lane = tid & 63;
    const int wave = tid >> 6;
    const int wr = wave >> 1, wc = wave & 1;
    const int rowBase = rb * 128;
    const int colBase = cb * 128;

    if (tid < 128) labR[tid] = labels[rowBase + tid];
    else           labC[tid - 128] = labels[colBase + tid - 128];

    const int c0 = wave * 2, c1 = wave * 2 + 1;
    const int srow = lane >> 2;
    const int scol = (lane & 3) * 8;
    const unsigned short* gA0 = fb16 + (size_t)(rowBase + c0 * 16 + srow) * D + scol;
    const unsigned short* gA1 = fb16 + (size_t)(rowBase + c1 * 16 + srow) * D + scol;
    const unsigned short* gB0 = fb16 + (size_t)(colBase + c0 * 16 + srow) * D + scol;
    const unsigned short* gB1 = fb16 + (size_t)(colBase + c1 * 16 + srow) * D + scol;
    unsigned short* lA0 = As + c0 * 512 + lane * 8;
    unsigned short* lA1 = As + c1 * 512 + lane * 8;
    unsigned short* lB0 = Bs + c0 * 512 + lane * 8;
    unsigned short* lB1 = Bs + c1 * 512 + lane * 8;

    const int q = lane >> 4;
    const int cIn = lane & 15;
    int aOff[4], bOff[4];
#pragma unroll
    for (int i = 0; i < 4; ++i) {
        aOff[i] = (wr * 64 + i * 16 + cIn) * 32 + q * 8;
        bOff[i] = (wc * 64 + i * 16 + cIn) * 32 + q * 8;
    }

    floatx4 acc[4][4] = {};
    const int KT = D >> 5;
    for (int kt = 0; kt < KT; ++kt) {
        const int kOff = kt * 32;
        __syncthreads();
        __builtin_amdgcn_global_load_lds((gvoid*)(gA0 + kOff), (svoid*)lA0, 16, 0, 0);
        __builtin_amdgcn_global_load_lds((gvoid*)(gA1 + kOff), (svoid*)lA1, 16, 0, 0);
        __builtin_amdgcn_global_load_lds((gvoid*)(gB0 + kOff), (svoid*)lB0, 16, 0, 0);
        __builtin_amdgcn_global_load_lds((gvoid*)(gB1 + kOff), (svoid*)lB1, 16, 0, 0);
        __syncthreads();

        short8 a[4], b[4];
#pragma unroll
        for (int i = 0; i < 4; ++i) a[i] = *(const short8*)(As + aOff[i]);
#pragma unroll
        for (int i = 0; i < 4; ++i) b[i] = *(const short8*)(Bs + bOff[i]);
#pragma unroll
        for (int i = 0; i < 4; ++i)
#pragma unroll
            for (int j = 0; j < 4; ++j)
                acc[i][j] = __builtin_amdgcn_mfma_f32_16x16x32_bf16(a[i], b[j], acc[i][j], 0, 0, 0);
    }

    int rLabv[16];
#pragma unroll
    for (int mi = 0; mi < 4; ++mi)
#pragma unroll
        for (int rr = 0; rr < 4; ++rr)
            rLabv[mi * 4 + rr] = labR[wr * 64 + mi * 16 + q * 4 + rr];
    int cLabv[4];
#pragma unroll
    for (int ni = 0; ni < 4; ++ni)
        cLabv[ni] = labC[wc * 64 + ni * 16 + cIn];

    {
        half8* dst = (half8*)(simh + (size_t)t * 16384 + (size_t)tid * 64);
#pragma unroll
        for (int mi = 0; mi < 4; ++mi) {
            half8 h0, h1;
#pragma unroll
            for (int ni = 0; ni < 2; ++ni)
#pragma unroll
                for (int rr = 0; rr < 4; ++rr) {
                    h0[ni * 4 + rr] = (_Float16)acc[mi][ni][rr];
                    h1[ni * 4 + rr] = (_Float16)acc[mi][ni + 2][rr];
                }
            dst[mi * 2] = h0;
            dst[mi * 2 + 1] = h1;
        }
    }

#pragma unroll
    for (int mi = 0; mi < 4; ++mi)
#pragma unroll
        for (int rr = 0; rr < 4; ++rr) {
            const int rLoc = wr * 64 + mi * 16 + q * 4 + rr;
            const int rLab = rLabv[mi * 4 + rr];
            float vmin = 1e30f, vmax = -1e30f;
#pragma unroll
            for (int ni = 0; ni < 4; ++ni) {
                float s = acc[mi][ni][rr];
                if (rLab == cLabv[ni]) {
                    if (s < 1.0f - EPSV) vmin = fminf(vmin, s);
                } else {
                    vmax = fmaxf(vmax, s);
                }
            }
#pragma unroll
            for (int off = 8; off; off >>= 1) {
                vmin = fminf(vmin, __shfl_xor(vmin, off, 16));
                vmax = fmaxf(vmax, __shfl_xor(vmax, off, 16));
            }
            if (cIn == 0) {
                if (vmin < 1e30f) atomicMin(&minp_ord[rowBase + rLoc], f2ord(vmin));
                if (vmax > -1e30f) atomicMax(&maxn_ord[rowBase + rLoc], f2ord(vmax));
            }
        }

    if (rb != cb) {
#pragma unroll
        for (int ni = 0; ni < 4; ++ni) {
            const int cLab = cLabv[ni];
            float vmin = 1e30f, vmax = -1e30f;
#pragma unroll
            for (int mi = 0; mi < 4; ++mi)
#pragma unroll
                for (int rr = 0; rr < 4; ++rr) {
                    float s = acc[mi][ni][rr];
                    if (rLabv[mi * 4 + rr] == cLab) {
                        if (s < 1.0f - EPSV) vmin = fminf(vmin, s);
                    } else {
                        vmax = fmaxf(vmax, s);
                    }
                }
            vmin = fminf(vmin, __shfl_xor(vmin, 16, 64));
            vmin = fminf(vmin, __shfl_xor(vmin, 32, 64));
            vmax = fmaxf(vmax, __shfl_xor(vmax, 16, 64));
            vmax = fmaxf(vmax, __shfl_xor(vmax, 32, 64));
            if (q == 0) {
                const int cLoc = wc * 64 + ni * 16 + cIn;
                if (vmin < 1e30f) atomicMin(&minp_ord[colBase + cLoc], f2ord(vmin));
                if (vmax > -1e30f) atomicMax(&maxn_ord[colBase + cLoc], f2ord(vmax));
            }
        }
    }
}

__global__ void k_sum2f(const _Float16* __restrict__ simh,
                        const int* __restrict__ labels,
                        const unsigned* __restrict__ minp_ord,
                        const unsigned* __restrict__ maxn_ord,
                        float* __restrict__ psum, float* __restrict__ nsum,
                        unsigned* __restrict__ done_cnt,
                        float* __restrict__ out,
                        int nb, int B) {
    __shared__ int labR[128], labC[128];
    __shared__ float mpR[128], mnR[128], mpC[128], mnC[128];
    __shared__ float red[4];
    __shared__ unsigned lastflag;

    int t = blockIdx.x;
    int rb = 0, rem = t;
    while (rem >= nb - rb) { rem -= nb - rb; ++rb; }
    const int cb = rb + rem;

    const int tid = threadIdx.x;
    const int lane = tid & 63;
    const int wave = tid >> 6;
    const int wr = wave >> 1, wc = wave & 1;
    const int rowBase = rb * 128;
    const int colBase = cb * 128;
    const int q = lane >> 4;
    const int cIn = lane & 15;

    if (tid < 128) {
        labR[tid] = labels[rowBase + tid];
        mpR[tid] = ord2f(minp_ord[rowBase + tid]) - MARGIN;
        mnR[tid] = ord2f(maxn_ord[rowBase + tid]) + MARGIN;
    } else {
        int j = tid - 128;
        labC[j] = labels[colBase + j];
        mpC[j] = ord2f(minp_ord[colBase + j]) - MARGIN;
        mnC[j] = ord2f(maxn_ord[colBase + j]) + MARGIN;
    }
    __syncthreads();

    int cLabv[4];
#pragma unroll
    for (int ni = 0; ni < 4; ++ni) cLabv[ni] = labC[wc * 64 + ni * 16 + cIn];

    const half8* src = (const half8*)(simh + (size_t)t * 16384 + (size_t)tid * 64);
    half8 hv[8];
#pragma unroll
    for (int v = 0; v < 8; ++v) hv[v] = src[v];

    float cps[4] = {}, cns[4] = {};
    const bool offd = (rb != cb);

#pragma unroll
    for (int mi = 0; mi < 4; ++mi)
#pragma unroll
        for (int rr = 0; rr < 4; ++rr) {
            const int rLoc = wr * 64 + mi * 16 + q * 4 + rr;
            const int rLab = labR[rLoc];
            const float gateN = mpR[rLoc];
            const float gateP = mnR[rLoc];
            float rp = 0.f, rn = 0.f;
#pragma unroll
            for (int ni = 0; ni < 4; ++ni) {
                const int idx = mi * 16 + ni * 4 + rr;
                const float s = (float)hv[idx >> 3][idx & 7];
                const int cLoc = wc * 64 + ni * 16 + cIn;
                if (rLab == cLabv[ni]) {
                    if (s < 1.0f - EPSV) {
                        float ev = __expf(-SCALE_POS * (s - THRESH));
                        if (s < gateP) rp += ev;
                        if (offd && s < mnC[cLoc]) cps[ni] += ev;
                    }
                } else {
                    float ev = __expf(SCALE_NEG * (s - THRESH));
                    if (s > gateN) rn += ev;
                    if (offd && s > mpC[cLoc]) cns[ni] += ev;
                }
            }
#pragma unroll
            for (int off = 8; off; off >>= 1) {
                rp += __shfl_xor(rp, off, 16);
                rn += __shfl_xor(rn, off, 16);
            }
            if (cIn == 0) {
                if (rp != 0.f) atomicAdd(&psum[rowBase + rLoc], rp);
                if (rn != 0.f) atomicAdd(&nsum[rowBase + rLoc], rn);
            }
        }
    if (offd) {
#pragma unroll
        for (int ni = 0; ni < 4; ++ni) {
            cps[ni] += __shfl_xor(cps[ni], 16, 64);
            cps[ni] += __shfl_xor(cps[ni], 32, 64);
            cns[ni] += __shfl_xor(cns[ni], 16, 64);
            cns[ni] += __shfl_xor(cns[ni], 32, 64);
            if (q == 0) {
                const int cLoc = wc * 64 + ni * 16 + cIn;
                if (cps[ni] != 0.f) atomicAdd(&psum[colBase + cLoc], cps[ni]);
                if (cns[ni] != 0.f) atomicAdd(&nsum[colBase + cLoc], cns[ni]);
            }
        }
    }

    __syncthreads();
    if (tid == 0) {
        unsigned prev = __hip_atomic_fetch_add(done_cnt, 1u, __ATOMIC_ACQ_REL,
                                               __HIP_MEMORY_SCOPE_AGENT);
        lastflag = (prev == (unsigned)(gridDim.x - 1)) ? 1u : 0u;
    }
    __syncthreads();
    if (lastflag) {
        float a = 0.f;
        for (int i = tid; i < B; i += 256) {
            float pv = atomicAdd(&psum[i], 0.0f);
            float nv = atomicAdd(&nsum[i], 0.0f);
            if (pv > 0.f && nv > 0.f)
                a += log1pf(pv) * (1.0f / SCALE_POS) + log1pf(nv) * (1.0f / SCALE_NEG);
        }
#pragma unroll
        for (int off = 32; off; off >>= 1) a += __shfl_down(a, off, 64);
        if ((tid & 63) == 0) red[tid >> 6] = a;
        __syncthreads();
        if (tid == 0) out[0] = (red[0] + red[1] + red[2] + red[3]) / (float)B;
    }
}

extern "C" void kernel_launch(void* const* d_in, const int* in_sizes, int n_in,
                              void* d_out, int out_size, void* d_ws, size_t ws_size,
                              hipStream_t stream) {
    const float* feats = (const float*)d_in[0];
    const int* labels = (const int*)d_in[1];
    int B = in_sizes[1];                  // 4096
    int D = in_sizes[0] / B;              // 1024
    int nb = B / 128;                     // 32
    const int NT = nb * (nb + 1) / 2;     // 528 (fallback grid)
    const int NBLK = nb + (nb * (nb - 1) / 2) * 2;  // 32 diag + 992 halves = 1024
    int total4 = B * D / 4;

    char* ws = (char*)d_ws;
    unsigned short* fb16 = (unsigned short*)ws;
    size_t off = (size_t)B * D * sizeof(unsigned short);
    unsigned* minp = (unsigned*)(ws + off); off += (size_t)B * 4;
    unsigned* maxn = (unsigned*)(ws + off); off += (size_t)B * 4;
    float* psum = (float*)(ws + off); off += (size_t)B * 4;
    float* nsum = (float*)(ws + off); off += (size_t)B * 4;
    unsigned* cnts = (unsigned*)(ws + off); off += 256;  // arrive[0..31], done@32, fb@33
    _Float16* simh = (_Float16*)(ws + ((off + 255) & ~(size_t)255));
    float* outp = (float*)d_out;

    k_init<<<(total4 + 255) / 256, 256, 0, stream>>>(feats, fb16, minp, maxn,
                                                     psum, nsum, cnts, total4, B);

    // ---- primary: fused kernel at 4 blocks/CU, relaxed-atomic sync ----
    unsigned* arrive = cnts;
    unsigned* done0 = cnts + 32;
    void* kargs[] = {
        (void*)&fb16, (void*)&labels, (void*)&minp, (void*)&maxn,
        (void*)&psum, (void*)&nsum, (void*)&arrive, (void*)&done0,
        (void*)&outp, (void*)&D, (void*)&nb, (void*)&B
    };
    hipError_t err = hipLaunchCooperativeKernel((const void*)(uintptr_t)&k_main,
                                                dim3(NBLK), dim3(256), kargs, 0, stream);
    if (err == hipSuccess) return;
    (void)hipGetLastError();  // clear error; fall back

    // ---- fallback: proven round-2/5 multi-kernel path ----
    k_gemm_sym<<<NT, 256, 0, stream>>>(fb16, labels, minp, maxn, simh, D, nb);
    k_sum2f<<<NT, 256, 0, stream>>>(simh, labels, minp, maxn, psum, nsum,
                                    cnts + 33, outp, nb, B);
}

// Round 7
// 149.523 us; speedup vs baseline: 1.3095x; 1.3095x over previous
//
#include <hip/hip_runtime.h>

typedef short short8 __attribute__((ext_vector_type(8)));
typedef _Float16 half8 __attribute__((ext_vector_type(8)));
typedef float floatx4 __attribute__((ext_vector_type(4)));
typedef __attribute__((address_space(1))) const void gvoid;
typedef __attribute__((address_space(3))) void svoid;

#define SCALE_POS 2.0f
#define SCALE_NEG 40.0f
#define THRESH 0.5f
#define MARGIN 0.1f
#define EPSV 1e-5f

__device__ __forceinline__ unsigned short f2bf(float f) {
    unsigned u = __float_as_uint(f);
    u += 0x7fffu + ((u >> 16) & 1u);   // round-to-nearest-even
    return (unsigned short)(u >> 16);
}
// order-preserving float<->uint map (no NaNs present)
__device__ __forceinline__ unsigned f2ord(float f) {
    unsigned u = __float_as_uint(f);
    return (u & 0x80000000u) ? ~u : (u | 0x80000000u);
}
__device__ __forceinline__ float ord2f(unsigned e) {
    unsigned v = (e & 0x80000000u) ? (e & 0x7fffffffu) : ~e;
    return __uint_as_float(v);
}

#define ORD_POS_INF 0xff800000u   // f2ord(+inf)
#define ORD_NEG_INF 0x007fffffu   // f2ord(-inf)

// ---- kernel 1: fp32 -> bf16 cast + stat/counter init ----
__global__ void k_init(const float* __restrict__ feats,
                       unsigned short* __restrict__ fb16,
                       unsigned* __restrict__ minp, unsigned* __restrict__ maxn,
                       float* __restrict__ psum, float* __restrict__ nsum,
                       unsigned* __restrict__ cnts,
                       int total4, int B) {
    int i = blockIdx.x * blockDim.x + threadIdx.x;
    if (i < total4) {
        float4 v = ((const float4*)feats)[i];
        ushort4 o;
        o.x = f2bf(v.x); o.y = f2bf(v.y); o.z = f2bf(v.z); o.w = f2bf(v.w);
        ((ushort4*)fb16)[i] = o;
    }
    if (i < B) {
        minp[i] = ORD_POS_INF;
        maxn[i] = ORD_NEG_INF;
        psum[i] = 0.f;
        nsum[i] = 0.f;
    }
    if (i < 64) cnts[i] = 0;
}

// =====================================================================
// kernel 2: symmetric GEMM, 528 upper-tri 128x128 tiles, 512 threads =
// 8 waves (2 row-halves x 4 col-quarters; wave = 64x32 = 4x2 MFMA tiles).
// Doubles resident waves/CU vs the 256-thread version (16.5 vs 8.2) --
// the R1/R2/R5 law says GEMM time ~ 1/(waves/CU). Same 16KB/K-iter
// staging, same 64 block-MFMAs per barrier-pair.
// Epilogue: row+col min-pos/max-neg stats (atomics) + fp16 tile store.
// =====================================================================
__global__ void __launch_bounds__(512, 4)
k_gemm_sym(const unsigned short* __restrict__ fb16,
           const int* __restrict__ labels,
           unsigned* __restrict__ minp_ord,
           unsigned* __restrict__ maxn_ord,
           _Float16* __restrict__ simh,
           int D, int nb) {
    __shared__ __align__(16) unsigned short As[128 * 32];  // 8 KB
    __shared__ __align__(16) unsigned short Bs[128 * 32];  // 8 KB
    __shared__ int labR[128], labC[128];

    int t = blockIdx.x;
    int rb = 0, rem = t;
    while (rem >= nb - rb) { rem -= nb - rb; ++rb; }
    const int cb = rb + rem;

    const int tid = threadIdx.x;
    const int lane = tid & 63;
    const int wave = tid >> 6;           // 0..7
    const int wr = wave >> 2;            // 0..1 : row half (64 rows)
    const int wc = wave & 3;             // 0..3 : col quarter (32 cols)
    const int rowBase = rb * 128;
    const int colBase = cb * 128;
    const int q = lane >> 4;
    const int cIn = lane & 15;

    if (tid < 128)      labR[tid] = labels[rowBase + tid];
    else if (tid < 256) labC[tid - 128] = labels[colBase + tid - 128];

    // staging: 16 chunks of 1KB (16 rows x 32 cols); wave handles 2 chunks.
    // chunks 0..7 -> As rows, 8..15 -> Bs rows.
    const int c0 = wave * 2, c1 = c0 + 1;
    const int srow = lane >> 2;
    const int scol = (lane & 3) * 8;
    const int b0 = (c0 < 8) ? rowBase : colBase;
    const int b1 = (c1 < 8) ? rowBase : colBase;
    const unsigned short* g0 = fb16 + (size_t)(b0 + (c0 & 7) * 16 + srow) * D + scol;
    const unsigned short* g1 = fb16 + (size_t)(b1 + (c1 & 7) * 16 + srow) * D + scol;
    unsigned short* l0 = ((c0 < 8) ? As : Bs) + (c0 & 7) * 512 + lane * 8;
    unsigned short* l1 = ((c1 < 8) ? As : Bs) + (c1 & 7) * 512 + lane * 8;

    int aOff[4], bOff[2];
#pragma unroll
    for (int i = 0; i < 4; ++i) aOff[i] = (wr * 64 + i * 16 + cIn) * 32 + q * 8;
#pragma unroll
    for (int j = 0; j < 2; ++j) bOff[j] = (wc * 32 + j * 16 + cIn) * 32 + q * 8;

    floatx4 acc[4][2] = {};

    const int KT = D >> 5;
    for (int kt = 0; kt < KT; ++kt) {
        const int kOff = kt * 32;
        __syncthreads();
        __builtin_amdgcn_global_load_lds((gvoid*)(g0 + kOff), (svoid*)l0, 16, 0, 0);
        __builtin_amdgcn_global_load_lds((gvoid*)(g1 + kOff), (svoid*)l1, 16, 0, 0);
        __syncthreads();

        short8 a[4], b[2];
#pragma unroll
        for (int i = 0; i < 4; ++i) a[i] = *(const short8*)(As + aOff[i]);
#pragma unroll
        for (int j = 0; j < 2; ++j) b[j] = *(const short8*)(Bs + bOff[j]);
#pragma unroll
        for (int i = 0; i < 4; ++i)
#pragma unroll
            for (int j = 0; j < 2; ++j)
                acc[i][j] = __builtin_amdgcn_mfma_f32_16x16x32_bf16(a[i], b[j], acc[i][j], 0, 0, 0);
    }

    int cLabv[2];
#pragma unroll
    for (int ni = 0; ni < 2; ++ni) cLabv[ni] = labC[wc * 32 + ni * 16 + cIn];

    // ---- fp16 tile store: thread-major, 32 contiguous halves ----
    {
        half8* dst = (half8*)(simh + (size_t)t * 16384 + (size_t)tid * 32);
#pragma unroll
        for (int mi = 0; mi < 4; ++mi) {
            half8 h;
#pragma unroll
            for (int ni = 0; ni < 2; ++ni)
#pragma unroll
                for (int rr = 0; rr < 4; ++rr)
                    h[ni * 4 + rr] = (_Float16)acc[mi][ni][rr];
            dst[mi] = h;
        }
    }

    // ---- row stats (reduce over this wave's 32 cols, then cIn shuffle) ----
#pragma unroll
    for (int mi = 0; mi < 4; ++mi)
#pragma unroll
        for (int rr = 0; rr < 4; ++rr) {
            const int rLoc = wr * 64 + mi * 16 + q * 4 + rr;
            const int rLab = labR[rLoc];
            float vmin = 1e30f, vmax = -1e30f;
#pragma unroll
            for (int ni = 0; ni < 2; ++ni) {
                float s = acc[mi][ni][rr];
                if (rLab == cLabv[ni]) {
                    if (s < 1.0f - EPSV) vmin = fminf(vmin, s);
                } else {
                    vmax = fmaxf(vmax, s);
                }
            }
#pragma unroll
            for (int off = 8; off; off >>= 1) {
                vmin = fminf(vmin, __shfl_xor(vmin, off, 16));
                vmax = fmaxf(vmax, __shfl_xor(vmax, off, 16));
            }
            if (cIn == 0) {
                if (vmin < 1e30f) atomicMin(&minp_ord[rowBase + rLoc], f2ord(vmin));
                if (vmax > -1e30f) atomicMax(&maxn_ord[rowBase + rLoc], f2ord(vmax));
            }
        }

    // ---- col stats via symmetry (off-diagonal tiles only) ----
    if (rb != cb) {
#pragma unroll
        for (int ni = 0; ni < 2; ++ni) {
            const int cLab = cLabv[ni];
            float vmin = 1e30f, vmax = -1e30f;
#pragma unroll
            for (int mi = 0; mi < 4; ++mi)
#pragma unroll
                for (int rr = 0; rr < 4; ++rr) {
                    float s = acc[mi][ni][rr];
                    if (labR[wr * 64 + mi * 16 + q * 4 + rr] == cLab) {
                        if (s < 1.0f - EPSV) vmin = fminf(vmin, s);
                    } else {
                        vmax = fmaxf(vmax, s);
                    }
                }
            vmin = fminf(vmin, __shfl_xor(vmin, 16, 64));
            vmin = fminf(vmin, __shfl_xor(vmin, 32, 64));
            vmax = fmaxf(vmax, __shfl_xor(vmax, 16, 64));
            vmax = fmaxf(vmax, __shfl_xor(vmax, 32, 64));
            if (q == 0) {
                const int cLoc = wc * 32 + ni * 16 + cIn;
                if (vmin < 1e30f) atomicMin(&minp_ord[colBase + cLoc], f2ord(vmin));
                if (vmax > -1e30f) atomicMax(&maxn_ord[colBase + cLoc], f2ord(vmax));
            }
        }
    }
}

// =====================================================================
// kernel 3: pass 2 (512 threads, layout matches k_gemm_sym's fp16 store)
// + fused last-block scalar reduction.
// =====================================================================
__global__ void __launch_bounds__(512, 4)
k_sum2f(const _Float16* __restrict__ simh,
        const int* __restrict__ labels,
        const unsigned* __restrict__ minp_ord,
        const unsigned* __restrict__ maxn_ord,
        float* __restrict__ psum, float* __restrict__ nsum,
        unsigned* __restrict__ done_cnt,
        float* __restrict__ out,
        int nb, int B) {
    __shared__ int labR[128], labC[128];
    __shared__ float mpR[128], mnR[128], mpC[128], mnC[128];
    __shared__ float red[8];
    __shared__ unsigned lastflag;

    int t = blockIdx.x;
    int rb = 0, rem = t;
    while (rem >= nb - rb) { rem -= nb - rb; ++rb; }
    const int cb = rb + rem;

    const int tid = threadIdx.x;
    const int lane = tid & 63;
    const int wave = tid >> 6;
    const int wr = wave >> 2;
    const int wc = wave & 3;
    const int rowBase = rb * 128;
    const int colBase = cb * 128;
    const int q = lane >> 4;
    const int cIn = lane & 15;

    if (tid < 128) {
        labR[tid] = labels[rowBase + tid];
        mpR[tid] = ord2f(minp_ord[rowBase + tid]) - MARGIN;   // neg kept if s > this
        mnR[tid] = ord2f(maxn_ord[rowBase + tid]) + MARGIN;   // pos kept if s < this
    } else if (tid < 256) {
        int j = tid - 128;
        labC[j] = labels[colBase + j];
        mpC[j] = ord2f(minp_ord[colBase + j]) - MARGIN;
        mnC[j] = ord2f(maxn_ord[colBase + j]) + MARGIN;
    }
    __syncthreads();

    int cLabv[2];
    float mpCv[2], mnCv[2];
#pragma unroll
    for (int ni = 0; ni < 2; ++ni) {
        const int cLoc = wc * 32 + ni * 16 + cIn;
        cLabv[ni] = labC[cLoc];
        mpCv[ni] = mpC[cLoc];
        mnCv[ni] = mnC[cLoc];
    }

    const half8* src = (const half8*)(simh + (size_t)t * 16384 + (size_t)tid * 32);
    half8 hv[4];
#pragma unroll
    for (int v = 0; v < 4; ++v) hv[v] = src[v];

    float cps[2] = {}, cns[2] = {};
    const bool offd = (rb != cb);

#pragma unroll
    for (int mi = 0; mi < 4; ++mi)
#pragma unroll
        for (int rr = 0; rr < 4; ++rr) {
            const int rLoc = wr * 64 + mi * 16 + q * 4 + rr;
            const int rLab = labR[rLoc];
            const float gateN = mpR[rLoc];
            const float gateP = mnR[rLoc];
            float rp = 0.f, rn = 0.f;
#pragma unroll
            for (int ni = 0; ni < 2; ++ni) {
                const float s = (float)hv[mi][ni * 4 + rr];
                if (rLab == cLabv[ni]) {
                    if (s < 1.0f - EPSV) {
                        float ev = __expf(-SCALE_POS * (s - THRESH));
                        if (s < gateP) rp += ev;
                        if (offd && s < mnCv[ni]) cps[ni] += ev;
                    }
                } else {
                    float ev = __expf(SCALE_NEG * (s - THRESH));
                    if (s > gateN) rn += ev;
                    if (offd && s > mpCv[ni]) cns[ni] += ev;
                }
            }
#pragma unroll
            for (int off = 8; off; off >>= 1) {
                rp += __shfl_xor(rp, off, 16);
                rn += __shfl_xor(rn, off, 16);
            }
            if (cIn == 0) {
                if (rp != 0.f) atomicAdd(&psum[rowBase + rLoc], rp);
                if (rn != 0.f) atomicAdd(&nsum[rowBase + rLoc], rn);
            }
        }
    if (offd) {
#pragma unroll
        for (int ni = 0; ni < 2; ++ni) {
            cps[ni] += __shfl_xor(cps[ni], 16, 64);
            cps[ni] += __shfl_xor(cps[ni], 32, 64);
            cns[ni] += __shfl_xor(cns[ni], 16, 64);
            cns[ni] += __shfl_xor(cns[ni], 32, 64);
            if (q == 0) {
                const int cLoc = wc * 32 + ni * 16 + cIn;
                if (cps[ni] != 0.f) atomicAdd(&psum[colBase + cLoc], cps[ni]);
                if (cns[ni] != 0.f) atomicAdd(&nsum[colBase + cLoc], cns[ni]);
            }
        }
    }

    // ---- last-block final reduction ----
    // __syncthreads() drains vmcnt for ALL waves -> this block's atomics
    // are complete at L2 before the increment below.
    __syncthreads();
    if (tid == 0) {
        unsigned prev = __hip_atomic_fetch_add(done_cnt, 1u, __ATOMIC_ACQ_REL,
                                               __HIP_MEMORY_SCOPE_AGENT);
        lastflag = (prev == (unsigned)(gridDim.x - 1)) ? 1u : 0u;
    }
    __syncthreads();
    if (lastflag) {
        float a = 0.f;
        for (int i = tid; i < B; i += 512) {
            float pv = atomicAdd(&psum[i], 0.0f);   // device-scope coherent read
            float nv = atomicAdd(&nsum[i], 0.0f);
            if (pv > 0.f && nv > 0.f)
                a += log1pf(pv) * (1.0f / SCALE_POS) + log1pf(nv) * (1.0f / SCALE_NEG);
        }
#pragma unroll
        for (int off = 32; off; off >>= 1) a += __shfl_down(a, off, 64);
        if ((tid & 63) == 0) red[tid >> 6] = a;
        __syncthreads();
        if (tid == 0) {
            float s = 0.f;
#pragma unroll
            for (int w = 0; w < 8; ++w) s += red[w];
            out[0] = s / (float)B;
        }
    }
}

extern "C" void kernel_launch(void* const* d_in, const int* in_sizes, int n_in,
                              void* d_out, int out_size, void* d_ws, size_t ws_size,
                              hipStream_t stream) {
    const float* feats = (const float*)d_in[0];
    const int* labels = (const int*)d_in[1];
    const int B = in_sizes[1];            // 4096
    const int D = in_sizes[0] / B;        // 1024
    const int nb = B / 128;               // 32
    const int NT = nb * (nb + 1) / 2;     // 528
    const int total4 = B * D / 4;

    char* ws = (char*)d_ws;
    unsigned short* fb16 = (unsigned short*)ws;
    size_t off = (size_t)B * D * sizeof(unsigned short);
    unsigned* minp = (unsigned*)(ws + off); off += (size_t)B * 4;
    unsigned* maxn = (unsigned*)(ws + off); off += (size_t)B * 4;
    float* psum = (float*)(ws + off); off += (size_t)B * 4;
    float* nsum = (float*)(ws + off); off += (size_t)B * 4;
    unsigned* cnts = (unsigned*)(ws + off); off += 256;   // done @0 (zeroed by k_init)
    _Float16* simh = (_Float16*)(ws + ((off + 255) & ~(size_t)255));
    float* outp = (float*)d_out;

    k_init<<<(total4 + 255) / 256, 256, 0, stream>>>(feats, fb16, minp, maxn,
                                                     psum, nsum, cnts, total4, B);

    k_gemm_sym<<<NT, 512, 0, stream>>>(fb16, labels, minp, maxn, simh, D, nb);

    k_sum2f<<<NT, 512, 0, stream>>>(simh, labels, minp, maxn, psum, nsum,
                                    &cnts[0], outp, nb, B);
}